// Round 9
// baseline (53.889 us; speedup 1.0000x reference)
//
#include <hip/hip_runtime.h>
#include <hip/hip_bf16.h>

typedef __attribute__((ext_vector_type(8))) short bf16x8;
typedef __attribute__((ext_vector_type(4))) float f32x4;
typedef __attribute__((ext_vector_type(2))) float f32x2;
typedef unsigned int uint32;
typedef unsigned short ushort_t;
typedef __attribute__((ext_vector_type(4))) uint32 u32x4;

#define SB0() __builtin_amdgcn_sched_barrier(0)
#define VMCNT0() do { asm volatile("s_waitcnt vmcnt(0)" ::: "memory"); SB0(); } while (0)

__device__ __forceinline__ ushort_t f2bf(float f) {
    unsigned int u = __float_as_uint(f);
    u = (u + 0x7FFFu + ((u >> 16) & 1u)) >> 16;
    return (ushort_t)u;
}

__device__ __forceinline__ uint32 cvt_pk_bf16(float lo, float hi) {
    uint32 r;
    asm("v_cvt_pk_bf16_f32 %0, %1, %2" : "=v"(r) : "v"(lo), "v"(hi));
    return r;
}

// Forced-issue 16B global load, 64-bit VGPR address + imm offset.
// Issue order pinned by asm volatile + SB0; completion via VMCNT0 only.
template<int IMM>
__device__ __forceinline__ u32x4 gload(const char* p) {
    u32x4 r;
    asm volatile("global_load_dwordx4 %0, %1, off offset:%2"
                 : "=v"(r) : "v"(p), "n"(IMM));
    return r;
}

__device__ __forceinline__ void gload_lds16(const void* g, void* l) {
    __builtin_amdgcn_global_load_lds(
        (const __attribute__((address_space(1))) uint32*)g,
        (__attribute__((address_space(3))) uint32*)l, 16, 0, 0);
}

// Fused prep: blocks 0..4095 transpose x (NCHW fp32 -> NHWC bf16, batch<->XCD),
// blocks 4096..4671 repack weight fragment-major:
// elem (tap, f=ft*16+p, c=ks*32+lu*8+j) -> (((tap*4+ks)*8+ft)*64 + lu*16+p)*8 + j
__global__ __launch_bounds__(256) void prep_all(const float* __restrict__ x,
                                                const float* __restrict__ w,
                                                ushort_t* __restrict__ xt,
                                                ushort_t* __restrict__ wT2) {
    int bi = blockIdx.x;
    int t = threadIdx.x;
    if (bi >= 4096) {
        int idx = (bi - 4096) * 256 + t;   // 0..147455
        int j  = idx & 7;
        int p  = (idx >> 3) & 15;
        int lu = (idx >> 7) & 3;
        int ft = (idx >> 9) & 7;
        int ks = (idx >> 12) & 3;
        int tap = idx >> 14;
        int f = ft * 16 + p;
        int c = ks * 32 + lu * 8 + j;
        wT2[idx] = f2bf(w[((size_t)f * 128 + c) * 9 + tap]);
        return;
    }
    __shared__ float tile[32][33];
    int b = bi & 7;
    int r2 = bi >> 3;
    int wb = r2 & 1, cb = (r2 >> 1) & 3, y = r2 >> 3;
    int lw = t & 31, lc = t >> 5;
    #pragma unroll
    for (int pass = 0; pass < 4; ++pass) {
        int c = cb * 32 + lc + pass * 8;
        tile[lc + pass * 8][lw] = x[(((size_t)b * 128 + c) * 64 + y) * 64 + wb * 32 + lw];
    }
    __syncthreads();
    int cc = t & 31, xl = t >> 5;
    #pragma unroll
    for (int pass = 0; pass < 4; ++pass) {
        int xll = xl + pass * 8;
        xt[(((size_t)b * 64 + y) * 64 + wb * 32 + xll) * 128 + cb * 32 + cc] =
            f2bf(tile[cc][xll]);
    }
}

__device__ __forceinline__ bf16x8 interp4(u32x4 c0, u32x4 c1, u32x4 c2, u32x4 c3,
                                          f32x4 wv) {
    uint32 rr[4];
    #pragma unroll
    for (int i = 0; i < 4; ++i) {
        f32x2 a, s;
        uint32 u = c0[i];
        a.x = __uint_as_float(u << 16); a.y = __uint_as_float(u & 0xffff0000u);
        s = a * wv.x;
        u = c1[i];
        a.x = __uint_as_float(u << 16); a.y = __uint_as_float(u & 0xffff0000u);
        s += a * wv.y;
        u = c2[i];
        a.x = __uint_as_float(u << 16); a.y = __uint_as_float(u & 0xffff0000u);
        s += a * wv.z;
        u = c3[i];
        a.x = __uint_as_float(u << 16); a.y = __uint_as_float(u & 0xffff0000u);
        s += a * wv.w;
        rr[i] = cvt_pk_bf16(s.x, s.y);
    }
    u32x4 q = {rr[0], rr[1], rr[2], rr[3]};
    return __builtin_bit_cast(bf16x8, q);
}

// Block = 512 thr = 8 waves = {4 pixel strips} x {2 K-groups}; tile = one
// (b,ho) row (64 px) x 128 F. tg0 owns ks0,1 (ch 0..63), tg1 owns ks2,3.
// A staged in LDS per tap (32 KB, dbuf) via global_load_lds; gathers are
// asm-issued and drained ONLY by vmcnt(0) at tap end -> spill-proof.
// 512 blocks x 2/CU = 16 waves/CU = 4 waves/SIMD, all resident.
__global__ __launch_bounds__(512, 4) void dcn_main(
    const float* __restrict__ offset, const float* __restrict__ mask,
    const ushort_t* __restrict__ xt, const ushort_t* __restrict__ wT2,
    float* __restrict__ out)
{
    __shared__ ushort_t Abuf[2][16384];  // 64 KB: A-tile double buffer
    __shared__ float  pws_l[9][64][4];   // corner weights*mask*valid
    __shared__ uint32 pos_l[9][64];      // packed (y0*64+x0) | (y1*64+x1)<<16

    int bi = blockIdx.x;
    int b = bi & 7, ho = bi >> 3;        // batch <-> XCD
    int t = threadIdx.x, lane = t & 63, wid = t >> 6;
    int strip = wid & 3, tg = wid >> 2;
    int p = lane & 15, lu = lane >> 4;
    int pix = strip * 16 + p;

    // ---- prologue: stage tap 0 (async) + sampling params ----
    {
        const ushort_t* s0 = wT2 + t * 8;
        #pragma unroll
        for (int r = 0; r < 4; ++r)
            gload_lds16(s0 + r * 4096, &Abuf[0][(r * 512 + t) * 8]);
    }
    for (int item = t; item < 576; item += 512) {
        int k = item >> 6, pi = item & 63;
        int ki = k / 3, kj = k - ki * 3;
        float dy = offset[(((size_t)b * 18 + 2 * k)     * 64 + ho) * 64 + pi];
        float dx = offset[(((size_t)b * 18 + 2 * k + 1) * 64 + ho) * 64 + pi];
        float m  = mask  [(((size_t)b * 9  + k)         * 64 + ho) * 64 + pi];
        float py = (float)(ho - 1 + ki) + dy;
        float px = (float)(pi - 1 + kj) + dx;
        float y0f = floorf(py), x0f = floorf(px);
        float ly = py - y0f, lx = px - x0f;
        float hy = 1.f - ly, hx = 1.f - lx;
        int y0 = (int)y0f, x0 = (int)x0f;
        int y1 = y0 + 1, x1 = x0 + 1;
        float vy0 = (y0 >= 0 && y0 < 64) ? 1.f : 0.f;
        float vy1 = (y1 >= 0 && y1 < 64) ? 1.f : 0.f;
        float vx0 = (x0 >= 0 && x0 < 64) ? 1.f : 0.f;
        float vx1 = (x1 >= 0 && x1 < 64) ? 1.f : 0.f;
        pws_l[k][pi][0] = hy * hx * m * vy0 * vx0;
        pws_l[k][pi][1] = hy * lx * m * vy0 * vx1;
        pws_l[k][pi][2] = ly * hx * m * vy1 * vx0;
        pws_l[k][pi][3] = ly * lx * m * vy1 * vx1;
        int y0c = min(max(y0, 0), 63), y1c = min(max(y1, 0), 63);
        int x0c = min(max(x0, 0), 63), x1c = min(max(x1, 0), 63);
        pos_l[k][pi] = (uint32)(y0c * 64 + x0c) | ((uint32)(y1c * 64 + x1c) << 16);
    }
    __syncthreads();   // drains S(0) (vmcnt) + publishes params

    const char* xb = (const char*)xt + (size_t)b * (64 * 64 * 256);
    uint32 cl = (uint32)(tg * 128 + lu * 16);  // gather byte offset in 256B pixel rec

    f32x4 acc[8];
    #pragma unroll
    for (int i = 0; i < 8; ++i) acc[i] = (f32x4){0.f, 0.f, 0.f, 0.f};

    f32x4 wv;
    const char *p00, *p01, *p10, *p11;
    auto tap_params = [&](int k) {
        uint32 pp = pos_l[k][pix];
        wv = *(const f32x4*)pws_l[k][pix];
        uint32 i00 = pp & 0xffffu, i11 = pp >> 16;
        uint32 o01 = (i00 & 0xffc0u) | (i11 & 63u);
        uint32 o10 = (i11 & 0xffc0u) | (i00 & 63u);
        p00 = xb + ((i00 << 8) + cl); p01 = xb + ((o01 << 8) + cl);
        p10 = xb + ((o10 << 8) + cl); p11 = xb + ((i11 << 8) + cl);
    };

    u32x4 g[4][2];
    #define ISSUE_G()                          \
        do {                                   \
            g[0][0] = gload<0>(p00);           \
            g[0][1] = gload<64>(p00);          \
            g[1][0] = gload<0>(p01);           \
            g[1][1] = gload<64>(p01);          \
            g[2][0] = gload<0>(p10);           \
            g[2][1] = gload<64>(p10);          \
            g[3][0] = gload<0>(p11);           \
            g[3][1] = gload<64>(p11);          \
        } while (0)

    // G(0): params are visible now
    tap_params(0);
    ISSUE_G();
    SB0();
    VMCNT0();   // G(0) ready

    #pragma unroll 1
    for (int tap = 0; tap < 9; ++tap) {
        // ---- interp: B fragments for this wave's two K-steps ----
        bf16x8 b0 = interp4(g[0][0], g[1][0], g[2][0], g[3][0], wv);
        bf16x8 b1 = interp4(g[0][1], g[1][1], g[2][1], g[3][1], wv);

        // ---- issue next tap's stage + gathers (fly under MFMA phase) ----
        if (tap < 8) {
            ushort_t* An = &Abuf[(tap + 1) & 1][0];
            const ushort_t* ss = wT2 + (size_t)(tap + 1) * 16384 + t * 8;
            #pragma unroll
            for (int r = 0; r < 4; ++r)
                gload_lds16(ss + r * 4096, &An[(r * 512 + t) * 8]);
            tap_params(tap + 1);
            ISSUE_G();
            SB0();
        }

        // ---- MFMA: 128F x 16 px, this wave's 2 K-steps from LDS ----
        const ushort_t* Ab = &Abuf[tap & 1][0];
        #pragma unroll
        for (int q = 0; q < 2; ++q) {
            int ks = tg * 2 + q;
            bf16x8 bb = q ? b1 : b0;
            #pragma unroll
            for (int ft = 0; ft < 8; ++ft) {
                bf16x8 aa = *(const bf16x8*)&Ab[((ks * 8 + ft) * 64 + lane) * 8];
                acc[ft] = __builtin_amdgcn_mfma_f32_16x16x32_bf16(aa, bb, acc[ft], 0, 0, 0);
            }
        }

        // ---- tap end: full drain (spill-proof) + raw barrier publishes stage ----
        if (tap < 8) {
            VMCNT0();
            __builtin_amdgcn_s_barrier();
            SB0();
        }
    }
    #undef ISSUE_G

    // ---- epilogue: 2-way K-split reduce via LDS (reuse Abuf), tg0 stores ----
    __syncthreads();   // everyone done with Abuf / MFMA reads
    float* red = (float*)&Abuf[0][0];  // [4 strips][128 f][17 pad]
    if (tg == 1) {
        #pragma unroll
        for (int ft = 0; ft < 8; ++ft)
            #pragma unroll
            for (int r = 0; r < 4; ++r) {
                int f = ft * 16 + lu * 4 + r;
                red[(strip * 128 + f) * 17 + p] = acc[ft][r];
            }
    }
    __syncthreads();
    if (tg == 0) {
        float* outb = out + (size_t)b * 128 * 4096 + ho * 64 + strip * 16 + p;
        #pragma unroll
        for (int ft = 0; ft < 8; ++ft)
            #pragma unroll
            for (int r = 0; r < 4; ++r) {
                int f = ft * 16 + lu * 4 + r;
                outb[(size_t)f * 4096] = acc[ft][r] + red[(strip * 128 + f) * 17 + p];
            }
    }
}

extern "C" void kernel_launch(void* const* d_in, const int* in_sizes, int n_in,
                              void* d_out, int out_size, void* d_ws, size_t ws_size,
                              hipStream_t stream) {
    const float* x      = (const float*)d_in[0];
    const float* offset = (const float*)d_in[1];
    const float* mask   = (const float*)d_in[2];
    const float* weight = (const float*)d_in[3];
    float* out = (float*)d_out;

    ushort_t* xt  = (ushort_t*)d_ws;                       // 8 MiB
    ushort_t* wT2 = xt + (size_t)8 * 64 * 64 * 128;        // 288 KiB
    if (ws_size < (size_t)(8 * 64 * 64 * 128 + 9 * 16384) * 2) return;

    prep_all<<<4672, 256, 0, stream>>>(x, weight, xt, wT2);
    dcn_main<<<512, 512, 0, stream>>>(offset, mask, xt, wT2, out);
}

// Round 10
// 42.425 us; speedup vs baseline: 1.2702x; 1.2702x over previous
//
#include <hip/hip_runtime.h>
#include <hip/hip_bf16.h>

typedef __attribute__((ext_vector_type(8))) short bf16x8;
typedef __attribute__((ext_vector_type(4))) float f32x4;
typedef __attribute__((ext_vector_type(2))) float f32x2;
typedef unsigned int uint32;
typedef unsigned short ushort_t;
typedef __attribute__((ext_vector_type(4))) uint32 u32x4;

__device__ __forceinline__ ushort_t f2bf(float f) {
    unsigned int u = __float_as_uint(f);
    u = (u + 0x7FFFu + ((u >> 16) & 1u)) >> 16;
    return (ushort_t)u;
}

__device__ __forceinline__ uint32 cvt_pk_bf16(float lo, float hi) {
    uint32 r;
    asm("v_cvt_pk_bf16_f32 %0, %1, %2" : "=v"(r) : "v"(lo), "v"(hi));
    return r;
}

__device__ __forceinline__ void gload_lds16(const void* g, void* l) {
    __builtin_amdgcn_global_load_lds(
        (const __attribute__((address_space(1))) uint32*)g,
        (__attribute__((address_space(3))) uint32*)l, 16, 0, 0);
}

// Fused prep:
//  blocks 0..4095: transpose x NCHW fp32 -> NHWC bf16, with per-record 16B
//    sub-chunk XOR swizzle: chunk (c>>3) stored at (c>>3)^(x&7). This makes the
//    later LDS-window ds_read_b128 bank-conflict-free while keeping the
//    global_load_lds staging linear (swizzle lives in the SOURCE layout).
//  blocks 4096..4671: repack weight fragment-major:
//    elem (tap, f=ft*16+p, c=ks*32+lu*8+j) -> (((tap*4+ks)*8+ft)*64+lu*16+p)*8+j
__global__ __launch_bounds__(256) void prep_all(const float* __restrict__ x,
                                                const float* __restrict__ w,
                                                ushort_t* __restrict__ xt,
                                                ushort_t* __restrict__ wT2) {
    int bi = blockIdx.x;
    int t = threadIdx.x;
    if (bi >= 4096) {
        int idx = (bi - 4096) * 256 + t;   // 0..147455
        int j  = idx & 7;
        int p  = (idx >> 3) & 15;
        int lu = (idx >> 7) & 3;
        int ft = (idx >> 9) & 7;
        int ks = (idx >> 12) & 3;
        int tap = idx >> 14;
        int f = ft * 16 + p;
        int c = ks * 32 + lu * 8 + j;
        wT2[idx] = f2bf(w[((size_t)f * 128 + c) * 9 + tap]);
        return;
    }
    __shared__ float tile[32][33];
    int b = bi & 7;
    int r2 = bi >> 3;
    int wb = r2 & 1, cb = (r2 >> 1) & 3, y = r2 >> 3;
    int lw = t & 31, lc = t >> 5;
    #pragma unroll
    for (int pass = 0; pass < 4; ++pass) {
        int c = cb * 32 + lc + pass * 8;
        tile[lc + pass * 8][lw] = x[(((size_t)b * 128 + c) * 64 + y) * 64 + wb * 32 + lw];
    }
    __syncthreads();
    int cc = t & 31, xl = t >> 5;
    #pragma unroll
    for (int pass = 0; pass < 4; ++pass) {
        int xll = xl + pass * 8;
        int xx = wb * 32 + xll;
        int c = cb * 32 + cc;
        int c2 = (((c >> 3) ^ (xx & 7)) << 3) | (c & 7);   // record-local swizzle
        xt[(((size_t)b * 64 + y) * 64 + xx) * 128 + c2] = f2bf(tile[cc][xll]);
    }
}

__device__ __forceinline__ bf16x8 interp4(u32x4 c0, u32x4 c1, u32x4 c2, u32x4 c3,
                                          f32x4 wv) {
    uint32 rr[4];
    #pragma unroll
    for (int i = 0; i < 4; ++i) {
        f32x2 a, s;
        uint32 u = c0[i];
        a.x = __uint_as_float(u << 16); a.y = __uint_as_float(u & 0xffff0000u);
        s = a * wv.x;
        u = c1[i];
        a.x = __uint_as_float(u << 16); a.y = __uint_as_float(u & 0xffff0000u);
        s += a * wv.y;
        u = c2[i];
        a.x = __uint_as_float(u << 16); a.y = __uint_as_float(u & 0xffff0000u);
        s += a * wv.z;
        u = c3[i];
        a.x = __uint_as_float(u << 16); a.y = __uint_as_float(u & 0xffff0000u);
        s += a * wv.w;
        rr[i] = cvt_pk_bf16(s.x, s.y);
    }
    u32x4 q = {rr[0], rr[1], rr[2], rr[3]};
    return __builtin_bit_cast(bf16x8, q);
}

// Block = 512 thr = 8 waves = {4 pixel strips} x {2 K-groups}; one (b,ho) row.
// x gathers come from a 5-row LDS window (staged coalesced once per block);
// corners whose row falls outside the window (~12%) take an exec-masked global
// fallback. A staged in LDS dbuf per tap. 155 KB LDS -> 1 block/CU.
__global__ __launch_bounds__(512, 2) void dcn_main(
    const float* __restrict__ offset, const float* __restrict__ mask,
    const ushort_t* __restrict__ xt, const ushort_t* __restrict__ wT2,
    float* __restrict__ out)
{
    __shared__ ushort_t xwin[5 * 64 * 128];  // 80 KB: swizzled x-window rows
    __shared__ ushort_t Abuf[2][16384];      // 64 KB: A-tile double buffer
    __shared__ float  pws_l[9][64][4];       // corner weights*mask*valid
    __shared__ uint32 pos_l[9][64];          // (y0*64+x0) | (y1*64+x1)<<16

    int bi = blockIdx.x;
    int b = bi & 7, ho = bi >> 3;            // batch <-> XCD
    int t = threadIdx.x, lane = t & 63, wid = t >> 6;
    int strip = wid & 3, tg = wid >> 2;
    int p = lane & 15, lu = lane >> 4;
    int pix = strip * 16 + p;
    int row0 = min(max(ho - 2, 0), 59);

    const char* xgb = (const char*)xt + (size_t)b * (64 * 64 * 256);

    // ---- prologue: stage window + A(0) (async), compute sampling params ----
    {
        const char* ws = xgb + ((size_t)row0 << 14);     // row0*64*256
        #pragma unroll
        for (int r = 0; r < 10; ++r)
            gload_lds16(ws + (r * 512 + t) * 16, (char*)xwin + (r * 512 + t) * 16);
        const ushort_t* s0 = wT2 + t * 8;
        #pragma unroll
        for (int r = 0; r < 4; ++r)
            gload_lds16(s0 + r * 4096, &Abuf[0][(r * 512 + t) * 8]);
    }
    for (int item = t; item < 576; item += 512) {
        int k = item >> 6, pi = item & 63;
        int ki = k / 3, kj = k - ki * 3;
        float dy = offset[(((size_t)b * 18 + 2 * k)     * 64 + ho) * 64 + pi];
        float dx = offset[(((size_t)b * 18 + 2 * k + 1) * 64 + ho) * 64 + pi];
        float m  = mask  [(((size_t)b * 9  + k)         * 64 + ho) * 64 + pi];
        float py = (float)(ho - 1 + ki) + dy;
        float px = (float)(pi - 1 + kj) + dx;
        float y0f = floorf(py), x0f = floorf(px);
        float ly = py - y0f, lx = px - x0f;
        float hy = 1.f - ly, hx = 1.f - lx;
        int y0 = (int)y0f, x0 = (int)x0f;
        int y1 = y0 + 1, x1 = x0 + 1;
        float vy0 = (y0 >= 0 && y0 < 64) ? 1.f : 0.f;
        float vy1 = (y1 >= 0 && y1 < 64) ? 1.f : 0.f;
        float vx0 = (x0 >= 0 && x0 < 64) ? 1.f : 0.f;
        float vx1 = (x1 >= 0 && x1 < 64) ? 1.f : 0.f;
        pws_l[k][pi][0] = hy * hx * m * vy0 * vx0;
        pws_l[k][pi][1] = hy * lx * m * vy0 * vx1;
        pws_l[k][pi][2] = ly * hx * m * vy1 * vx0;
        pws_l[k][pi][3] = ly * lx * m * vy1 * vx1;
        int y0c = min(max(y0, 0), 63), y1c = min(max(y1, 0), 63);
        int x0c = min(max(x0, 0), 63), x1c = min(max(x1, 0), 63);
        pos_l[k][pi] = (uint32)(y0c * 64 + x0c) | ((uint32)(y1c * 64 + x1c) << 16);
    }
    __syncthreads();   // window + A(0) + params ready

    f32x4 acc[8];
    #pragma unroll
    for (int i = 0; i < 8; ++i) acc[i] = (f32x4){0.f, 0.f, 0.f, 0.f};

    int cl = tg * 128 + lu * 16;

    #pragma unroll 1
    for (int tap = 0; tap < 9; ++tap) {
        // ---- stage next tap's A into the other buffer (flies under this tap) ----
        if (tap < 8) {
            ushort_t* An = &Abuf[(tap + 1) & 1][0];
            const ushort_t* ss = wT2 + (size_t)(tap + 1) * 16384 + t * 8;
            #pragma unroll
            for (int r = 0; r < 4; ++r)
                gload_lds16(ss + r * 4096, &An[(r * 512 + t) * 8]);
        }

        // ---- gather 4 corners x 2 chunk-halves from the LDS window ----
        uint32 pp = pos_l[tap][pix];
        f32x4 wv = *(const f32x4*)pws_l[tap][pix];
        int i00 = pp & 0xffffu, i11 = pp >> 16;
        int y0c = i00 >> 6, x0c = i00 & 63;
        int y1c = i11 >> 6, x1c = i11 & 63;

        u32x4 g[4][2];
        #pragma unroll
        for (int c = 0; c < 4; ++c) {
            int yc = (c < 2) ? y0c : y1c;
            int xc = (c & 1) ? x1c : x0c;
            int rl = yc - row0;
            int sw = (xc & 7) << 4;
            int o0 = cl ^ sw;
            int o1 = (cl + 64) ^ sw;
            bool inw = (unsigned)rl < 5u;
            const char* lp = (const char*)xwin + (inw ? ((rl * 64 + xc) << 8) : 0);
            g[c][0] = *(const u32x4*)(lp + o0);
            g[c][1] = *(const u32x4*)(lp + o1);
            if (!inw) {   // rare row-out-of-window fallback (exec-masked)
                const char* gp = xgb + ((size_t)(yc * 64 + xc) << 8);
                g[c][0] = *(const u32x4*)(gp + o0);
                g[c][1] = *(const u32x4*)(gp + o1);
            }
        }

        bf16x8 b0 = interp4(g[0][0], g[1][0], g[2][0], g[3][0], wv);
        bf16x8 b1 = interp4(g[0][1], g[1][1], g[2][1], g[3][1], wv);

        // ---- MFMA: 128F x 16 px, this wave's 2 K-steps from LDS ----
        const ushort_t* Ab = &Abuf[tap & 1][0];
        #pragma unroll
        for (int q = 0; q < 2; ++q) {
            int ks = tg * 2 + q;
            bf16x8 bb = q ? b1 : b0;
            #pragma unroll
            for (int ft = 0; ft < 8; ++ft) {
                bf16x8 aa = *(const bf16x8*)&Ab[((ks * 8 + ft) * 64 + lane) * 8];
                acc[ft] = __builtin_amdgcn_mfma_f32_16x16x32_bf16(aa, bb, acc[ft], 0, 0, 0);
            }
        }

        __syncthreads();   // drains stage; publishes Abuf[(tap+1)&1]
    }

    // ---- epilogue: 2-way K-split reduce via LDS (reuse Abuf), tg0 stores ----
    float* red = (float*)&Abuf[0][0];  // [4 strips][128 f][17 pad] = 34 KB < 64 KB
    if (tg == 1) {
        #pragma unroll
        for (int ft = 0; ft < 8; ++ft)
            #pragma unroll
            for (int r = 0; r < 4; ++r) {
                int f = ft * 16 + lu * 4 + r;
                red[(strip * 128 + f) * 17 + p] = acc[ft][r];
            }
    }
    __syncthreads();
    if (tg == 0) {
        float* outb = out + (size_t)b * 128 * 4096 + ho * 64 + strip * 16 + p;
        #pragma unroll
        for (int ft = 0; ft < 8; ++ft)
            #pragma unroll
            for (int r = 0; r < 4; ++r) {
                int f = ft * 16 + lu * 4 + r;
                outb[(size_t)f * 4096] = acc[ft][r] + red[(strip * 128 + f) * 17 + p];
            }
    }
}

extern "C" void kernel_launch(void* const* d_in, const int* in_sizes, int n_in,
                              void* d_out, int out_size, void* d_ws, size_t ws_size,
                              hipStream_t stream) {
    const float* x      = (const float*)d_in[0];
    const float* offset = (const float*)d_in[1];
    const float* mask   = (const float*)d_in[2];
    const float* weight = (const float*)d_in[3];
    float* out = (float*)d_out;

    ushort_t* xt  = (ushort_t*)d_ws;                       // 8 MiB (swizzled NHWC)
    ushort_t* wT2 = xt + (size_t)8 * 64 * 64 * 128;        // 288 KiB
    if (ws_size < (size_t)(8 * 64 * 64 * 128 + 9 * 16384) * 2) return;

    prep_all<<<4672, 256, 0, stream>>>(x, weight, xt, wT2);
    dcn_main<<<512, 512, 0, stream>>>(offset, mask, xt, wT2, out);
}